// Round 4
// baseline (137.789 us; speedup 1.0000x reference)
//
#include <hip/hip_runtime.h>

// dist[pix, o] = ||x[pix]||^2 + ||omega[o]||^2 - 2 * x.omega
// M = 262144 pixels, O = 256 protos, D = 64.
// Round-4: LDS-transposed epilogue. MFMA C-tiles are scattered (64B islands at
// 1KiB stride) -> DRAM row-buffer hostile. Stage final values in LDS (XOR
// swizzle), read back pixel-major so every global store instr writes one full
// 1KiB contiguous pixel row; each wave streams 16KiB linear runs.
// omega bf16 fragments live in registers (128 VGPR); p2 in a 1KiB LDS
// broadcast table. 65KiB LDS -> 2 blocks/CU = 8 waves/CU.

typedef __attribute__((ext_vector_type(4))) float f32x4;
typedef __attribute__((ext_vector_type(8))) short s16x8;

constexpr int D_ = 64;
constexpr int O_ = 256;
constexpr int M_ = 16 * 128 * 128;            // 262144
constexpr int ITERS = 4;
constexpr int PIX_PER_BLOCK = 4 * 16 * ITERS; // 256
constexpr int NBLOCKS = M_ / PIX_PER_BLOCK;   // 1024

__device__ __forceinline__ unsigned short f2bf(float f) {
    unsigned u = __builtin_bit_cast(unsigned, f);
    u += 0x7FFFu + ((u >> 16) & 1u);
    return (unsigned short)(u >> 16);
}

__global__ __launch_bounds__(256, 2) void dist_kernel(
    const float* __restrict__ x,
    const float* __restrict__ om,
    float* __restrict__ out)
{
    __shared__ float stag[4][16 * 256];        // 64 KiB: per-wave transpose buffer
    __shared__ __align__(16) float lp2[O_];    // 1 KiB

    const int tid  = threadIdx.x;
    const int wave = tid >> 6;
    const int lane = tid & 63;
    const int lr   = lane & 15;   // A-frag: proto-in-tile ; B-frag: pixel-in-tile
    const int lg   = lane >> 4;   // k-group

    // ---------- once: omega -> bf16 A-fragments in REGISTERS + p2 -> LDS ----
    s16x8 Af[16][2];
#pragma unroll
    for (int t = 0; t < 16; ++t) {
        const float* src = om + (t * 16 + lr) * D_ + lg * 8;
        f32x4 v0 = *(const f32x4*)(src);
        f32x4 v1 = *(const f32x4*)(src + 4);
        f32x4 v2 = *(const f32x4*)(src + 32);
        f32x4 v3 = *(const f32x4*)(src + 36);
        float p2p = 0.f;
        s16x8 f0, f1;
#pragma unroll
        for (int j = 0; j < 4; ++j) {
            f0[j]     = (short)f2bf(v0[j]); p2p += v0[j] * v0[j];
            f0[4 + j] = (short)f2bf(v1[j]); p2p += v1[j] * v1[j];
            f1[j]     = (short)f2bf(v2[j]); p2p += v2[j] * v2[j];
            f1[4 + j] = (short)f2bf(v3[j]); p2p += v3[j] * v3[j];
        }
        Af[t][0] = f0;
        Af[t][1] = f1;
        p2p += __shfl_xor(p2p, 16);
        p2p += __shfl_xor(p2p, 32);
        if (lg == 0) lp2[t * 16 + lr] = p2p;   // identical values from all waves
    }
    __syncthreads();

    const int pix0 = blockIdx.x * PIX_PER_BLOCK;
    const int xoff = lr * D_ + lg * 8;
    float* const stg = &stag[wave][0];

    f32x4 bufA[4], bufB[4];

    // prologue: load iteration 0
    {
        const float* xs = x + (size_t)(pix0 + wave * 16) * D_ + xoff;
        bufA[0] = __builtin_nontemporal_load((const f32x4*)(xs));
        bufA[1] = __builtin_nontemporal_load((const f32x4*)(xs + 4));
        bufA[2] = __builtin_nontemporal_load((const f32x4*)(xs + 32));
        bufA[3] = __builtin_nontemporal_load((const f32x4*)(xs + 36));
    }

    auto body = [&](const f32x4* cur, f32x4* nxt, int it, bool prefetch) {
        // ---- cvt current x -> bf16 B-fragments + exact ||x||^2 (pixel lr)
        s16x8 Bx0, Bx1;
        float x2p = 0.f;
#pragma unroll
        for (int j = 0; j < 4; ++j) {
            Bx0[j]     = (short)f2bf(cur[0][j]); x2p += cur[0][j] * cur[0][j];
            Bx0[4 + j] = (short)f2bf(cur[1][j]); x2p += cur[1][j] * cur[1][j];
            Bx1[j]     = (short)f2bf(cur[2][j]); x2p += cur[2][j] * cur[2][j];
            Bx1[4 + j] = (short)f2bf(cur[3][j]); x2p += cur[3][j] * cur[3][j];
        }
        x2p += __shfl_xor(x2p, 16);
        x2p += __shfl_xor(x2p, 32);

        // ---- issue next iteration's x loads BEFORE this iter's stores
        if (prefetch) {
            const float* xs = x + (size_t)(pix0 + (it + 1) * 64 + wave * 16) * D_ + xoff;
            nxt[0] = __builtin_nontemporal_load((const f32x4*)(xs));
            nxt[1] = __builtin_nontemporal_load((const f32x4*)(xs + 4));
            nxt[2] = __builtin_nontemporal_load((const f32x4*)(xs + 32));
            nxt[3] = __builtin_nontemporal_load((const f32x4*)(xs + 36));
        }

        const int rbase = pix0 + it * 64 + wave * 16;

        // ---- compute 16 proto-tiles; final values -> LDS (swizzled)
#pragma unroll
        for (int t = 0; t < 16; ++t) {
            f32x4 acc = {0.f, 0.f, 0.f, 0.f};
            acc = __builtin_amdgcn_mfma_f32_16x16x32_bf16(Af[t][0], Bx0, acc, 0, 0, 0);
            acc = __builtin_amdgcn_mfma_f32_16x16x32_bf16(Af[t][1], Bx1, acc, 0, 0, 0);
            const f32x4 b4 = *(const f32x4*)&lp2[t * 16 + lg * 4];  // broadcast
            f32x4 val;
#pragma unroll
            for (int j = 0; j < 4; ++j)
                val[j] = (x2p + b4[j]) - 2.f * acc[j];
            // pixel row lr, logical dwords t*16+lg*4 .. +3, XOR-swizzled
            const int wIdx = (t * 16 + lg * 4) ^ ((lr & 7) << 2);
            *(f32x4*)&stg[lr * 256 + wIdx] = val;
        }

        // ---- read back pixel-major: one full 1KiB pixel row per store instr
#pragma unroll
        for (int p = 0; p < 16; ++p) {
            const int rIdx = (lane * 4) ^ ((p & 7) << 2);
            f32x4 v = *(const f32x4*)&stg[p * 256 + rIdx];
            __builtin_nontemporal_store(
                v, (f32x4*)(out + (size_t)(rbase + p) * O_ + lane * 4));
        }
    };

    body(bufA, bufB, 0, true);
    body(bufB, bufA, 1, true);
    body(bufA, bufB, 2, true);
    body(bufB, bufA, 3, false);
}

extern "C" void kernel_launch(void* const* d_in, const int* in_sizes, int n_in,
                              void* d_out, int out_size, void* d_ws, size_t ws_size,
                              hipStream_t stream) {
    const float* x  = (const float*)d_in[0];   // [16,128,128,64] fp32
    const float* om = (const float*)d_in[1];   // [256,64] fp32
    float* out = (float*)d_out;                // [16,128,128,256,1] fp32

    dist_kernel<<<dim3(NBLOCKS), dim3(256), 0, stream>>>(x, om, out);
}

// Round 5
// 79.139 us; speedup vs baseline: 1.7411x; 1.7411x over previous
//
#include <hip/hip_runtime.h>

// dist[pix, o] = ||x[pix]||^2 + ||omega[o]||^2 - 2 * x.omega
// M = 262144 pixels, O = 256 protos, D = 64.
// Round-5: EXACT round-2 structure (LDS omega fragments, swapped-operand MFMA,
// dwordx4 stores, 4 waves/SIMD). Single change: stores are PLAIN (write-back
// through L2) instead of nontemporal. Theory: nt stores bypass L2's
// partial-line merge, so our 64B-per-pixel store chunks hit DRAM as partial
// writes (ECC RMW / granule waste) -> ~2x write cost. Plain stores let L2
// merge chunks into full 128B lines before streaming out.

typedef __attribute__((ext_vector_type(4))) float f32x4;
typedef __attribute__((ext_vector_type(8))) short s16x8;
typedef __attribute__((ext_vector_type(4))) unsigned int u32x4;

constexpr int D_ = 64;
constexpr int O_ = 256;
constexpr int M_ = 16 * 128 * 128;           // 262144
constexpr int ITERS = 4;
constexpr int PIX_PER_BLOCK = 4 * 16 * ITERS; // 256
constexpr int NBLOCKS = M_ / PIX_PER_BLOCK;   // 1024

__device__ __forceinline__ unsigned short f2bf(float f) {
    // round-to-nearest-even fp32 -> bf16
    unsigned u = __builtin_bit_cast(unsigned, f);
    u += 0x7FFFu + ((u >> 16) & 1u);
    return (unsigned short)(u >> 16);
}

__global__ __launch_bounds__(256, 4) void dist_kernel(
    const float* __restrict__ x,
    const float* __restrict__ om,
    float* __restrict__ out)
{
    // [ (t*2+s)*64 + lane ] : per-lane 16B bf16 A-fragment of proto-tile t, k-step s
    __shared__ u32x4 lfrag[32 * 64];          // 32 KiB
    __shared__ __align__(16) float lp2[O_];   // 1 KiB

    const int tid  = threadIdx.x;
    const int wave = tid >> 6;
    const int lane = tid & 63;
    const int lr   = lane & 15;   // A-frag: proto-in-tile ; B-frag/out: pixel-in-tile
    const int lg   = lane >> 4;   // k-group

    // ---------- once per block: omega -> bf16 fragments + p2, into LDS ------
#pragma unroll
    for (int tt = 0; tt < 4; ++tt) {
        const int t = wave * 4 + tt;
        const float* src = om + (t * 16 + lr) * D_ + lg * 8;
        f32x4 v0 = *(const f32x4*)(src);
        f32x4 v1 = *(const f32x4*)(src + 4);
        f32x4 v2 = *(const f32x4*)(src + 32);
        f32x4 v3 = *(const f32x4*)(src + 36);
        float p2p = 0.f;
        s16x8 f0, f1;
#pragma unroll
        for (int j = 0; j < 4; ++j) {
            f0[j]     = (short)f2bf(v0[j]); p2p += v0[j] * v0[j];
            f0[4 + j] = (short)f2bf(v1[j]); p2p += v1[j] * v1[j];
            f1[j]     = (short)f2bf(v2[j]); p2p += v2[j] * v2[j];
            f1[4 + j] = (short)f2bf(v3[j]); p2p += v3[j] * v3[j];
        }
        lfrag[(t * 2 + 0) * 64 + lane] = __builtin_bit_cast(u32x4, f0);
        lfrag[(t * 2 + 1) * 64 + lane] = __builtin_bit_cast(u32x4, f1);
        p2p += __shfl_xor(p2p, 16);
        p2p += __shfl_xor(p2p, 32);
        if (lg == 0) lp2[t * 16 + lr] = p2p;   // lanes 0..15, conflict-free
    }
    __syncthreads();

    // ---------- steady state: 16 pixels per wave per iteration --------------
    const int pix0 = blockIdx.x * PIX_PER_BLOCK;
    for (int it = 0; it < ITERS; ++it) {
        const int rbase = pix0 + it * 64 + wave * 16;

        // B-frag (x): lane holds pixel (rbase+lr), k = lg*8.. (+s*32)
        const float* xs = x + (rbase + lr) * D_ + lg * 8;
        f32x4 a0 = __builtin_nontemporal_load((const f32x4*)(xs));
        f32x4 a1 = __builtin_nontemporal_load((const f32x4*)(xs + 4));
        f32x4 a2 = __builtin_nontemporal_load((const f32x4*)(xs + 32));
        f32x4 a3 = __builtin_nontemporal_load((const f32x4*)(xs + 36));
        s16x8 Bx0, Bx1;
        float x2p = 0.f;
#pragma unroll
        for (int j = 0; j < 4; ++j) {
            Bx0[j]     = (short)f2bf(a0[j]); x2p += a0[j] * a0[j];
            Bx0[4 + j] = (short)f2bf(a1[j]); x2p += a1[j] * a1[j];
            Bx1[j]     = (short)f2bf(a2[j]); x2p += a2[j] * a2[j];
            Bx1[4 + j] = (short)f2bf(a3[j]); x2p += a3[j] * a3[j];
        }
        // full ||x||^2 of pixel (rbase+lr); col of C is lr so no re-shuffle
        x2p += __shfl_xor(x2p, 16);
        x2p += __shfl_xor(x2p, 32);

        float* obase = out + (size_t)(rbase + lr) * O_;

#pragma unroll 4
        for (int t = 0; t < 16; ++t) {
            s16x8 A0 = __builtin_bit_cast(s16x8, lfrag[(t * 2 + 0) * 64 + lane]);
            s16x8 A1 = __builtin_bit_cast(s16x8, lfrag[(t * 2 + 1) * 64 + lane]);
            f32x4 acc = {0.f, 0.f, 0.f, 0.f};
            acc = __builtin_amdgcn_mfma_f32_16x16x32_bf16(A0, Bx0, acc, 0, 0, 0);
            acc = __builtin_amdgcn_mfma_f32_16x16x32_bf16(A1, Bx1, acc, 0, 0, 0);
            // C layout: row(=proto) = lg*4 + j, col(=pixel) = lr
            const f32x4 b4 = *(const f32x4*)&lp2[t * 16 + lg * 4];  // broadcast
            f32x4 val;
#pragma unroll
            for (int j = 0; j < 4; ++j)
                val[j] = (x2p + b4[j]) - 2.f * acc[j];
            // PLAIN store (write-back through L2) — the one change vs round 2
            *(f32x4*)(obase + t * 16 + lg * 4) = val;
        }
    }
}

extern "C" void kernel_launch(void* const* d_in, const int* in_sizes, int n_in,
                              void* d_out, int out_size, void* d_ws, size_t ws_size,
                              hipStream_t stream) {
    const float* x  = (const float*)d_in[0];   // [16,128,128,64] fp32
    const float* om = (const float*)d_in[1];   // [256,64] fp32
    float* out = (float*)d_out;                // [16,128,128,256,1] fp32

    dist_kernel<<<dim3(NBLOCKS), dim3(256), 0, stream>>>(x, om, out);
}